// Round 1
// baseline (345.949 us; speedup 1.0000x reference)
//
#include <hip/hip_runtime.h>
#include <hip/hip_bf16.h>

// Problem: B=32, C=128, HW=64*64=4096.
// out[b,j,n] = sum_i softmax_n(V)[i,n] * gd[i,j]
// gd[i,j]    = (1/hw) * sum_n softmax_n(B)[i,n] * A[j,n]
// Restructure: A eliminated via T[i,c] = sum_n expB[i,n]*x[c,n]:
//   gd[i,j] = (T[i,:]/ZB_i . wA[j,:] + bA[j]) / hw
//   G[i,j]  = gd[i,j] / ZV_i ;  out[j,n] = sum_i expV[i,n] * G[i,j]

#define B_  32
#define C_  128
#define HW_ 4096
#define R_  256   // 2*C rows (B-proj rows 0..127, V-proj rows 128..255)

__device__ __forceinline__ unsigned short f2bf(float f) {
    unsigned int u = __float_as_uint(f);
    u += 0x7fffu + ((u >> 16) & 1u);          // RNE to bf16
    return (unsigned short)(u >> 16);
}

__device__ __forceinline__ void unpack8(uint4 v, float* o) {
    o[0] = __uint_as_float(v.x << 16); o[1] = __uint_as_float(v.x & 0xffff0000u);
    o[2] = __uint_as_float(v.y << 16); o[3] = __uint_as_float(v.y & 0xffff0000u);
    o[4] = __uint_as_float(v.z << 16); o[5] = __uint_as_float(v.z & 0xffff0000u);
    o[6] = __uint_as_float(v.w << 16); o[7] = __uint_as_float(v.w & 0xffff0000u);
}

// K1: E = [wB;wV] @ x + bias ; store exp(E) as bf16 ; row sums of exp -> Zcat.
// grid (32 ntiles, 4 rowtiles, 32 b), block 256. Tile 64 rows x 128 n, K=128.
__global__ __launch_bounds__(256) void k1_bv(
    const float* __restrict__ x, const float* __restrict__ wB, const float* __restrict__ bB,
    const float* __restrict__ wV, const float* __restrict__ bV,
    unsigned short* __restrict__ expE, float* __restrict__ Zcat)
{
    const int t = threadIdx.x;
    const int tx = t & 15, ty = t >> 4;
    const int b = blockIdx.z;
    const int rowTile = blockIdx.y;          // 0..3
    const int nb = blockIdx.x * 128;

    const float* wSrc = (rowTile < 2) ? wB : wV;
    const float* bSrc = (rowTile < 2) ? bB : bV;
    const int rowBase  = (rowTile & 1) * 64;  // within the 128-row weight
    const int gRowBase = rowTile * 64;        // within 256-row expE

    __shared__ float Wl[64][36];    // [row][k] row-major, pad 36 (2-way max)
    __shared__ float Xl[32][132];   // [k][n] k-major, pad 132

    float acc[4][8];
#pragma unroll
    for (int i = 0; i < 4; ++i)
#pragma unroll
        for (int j = 0; j < 8; ++j) acc[i][j] = 0.f;

    const float* xb = x + (size_t)b * C_ * HW_;

    for (int k0 = 0; k0 < 128; k0 += 32) {
        __syncthreads();
#pragma unroll
        for (int it = 0; it < 2; ++it) {
            int idx = it * 256 + t;
            int row = idx >> 3, kq = (idx & 7) << 2;
            *(float4*)&Wl[row][kq] = *(const float4*)&wSrc[(rowBase + row) * 128 + k0 + kq];
        }
#pragma unroll
        for (int it = 0; it < 4; ++it) {
            int idx = it * 256 + t;
            int k = idx >> 5, nq = (idx & 31) << 2;
            *(float4*)&Xl[k][nq] = *(const float4*)&xb[(size_t)(k0 + k) * HW_ + nb + nq];
        }
        __syncthreads();
#pragma unroll
        for (int k = 0; k < 32; k += 4) {
            float wr[4][4];
#pragma unroll
            for (int rr = 0; rr < 4; ++rr) {
                float4 wv = *(const float4*)&Wl[rr * 16 + ty][k];
                wr[rr][0] = wv.x; wr[rr][1] = wv.y; wr[rr][2] = wv.z; wr[rr][3] = wv.w;
            }
#pragma unroll
            for (int d = 0; d < 4; ++d) {
                float4 xa = *(const float4*)&Xl[k + d][tx * 8];
                float4 xc = *(const float4*)&Xl[k + d][tx * 8 + 4];
                float xs[8] = {xa.x, xa.y, xa.z, xa.w, xc.x, xc.y, xc.z, xc.w};
#pragma unroll
                for (int rr = 0; rr < 4; ++rr)
#pragma unroll
                    for (int nn = 0; nn < 8; ++nn)
                        acc[rr][nn] = fmaf(wr[rr][d], xs[nn], acc[rr][nn]);
            }
        }
    }

#pragma unroll
    for (int rr = 0; rr < 4; ++rr) {
        int lr = rr * 16 + ty;
        int gr = gRowBase + lr;
        float bias = bSrc[rowBase + lr];
        float e[8]; float rs = 0.f;
#pragma unroll
        for (int nn = 0; nn < 8; ++nn) { e[nn] = __expf(acc[rr][nn] + bias); rs += e[nn]; }
        unsigned int pk[4];
#pragma unroll
        for (int q = 0; q < 4; ++q)
            pk[q] = (unsigned int)f2bf(e[2 * q]) | ((unsigned int)f2bf(e[2 * q + 1]) << 16);
        *(uint4*)&expE[((size_t)b * R_ + gr) * HW_ + nb + tx * 8] = make_uint4(pk[0], pk[1], pk[2], pk[3]);
        rs += __shfl_down(rs, 8, 16);
        rs += __shfl_down(rs, 4, 16);
        rs += __shfl_down(rs, 2, 16);
        rs += __shfl_down(rs, 1, 16);
        if (tx == 0) atomicAdd(&Zcat[b * R_ + gr], rs);
    }
}

// K3: T[b,i,c] += sum_{n in chunk} expB[b,i,n] * x[b,c,n].
// grid (32 b, 16 chunks of 256), block 256. Tile 128i x 128c, 8x8/thread.
__global__ __launch_bounds__(256) void k3_T(
    const unsigned short* __restrict__ expE, const float* __restrict__ x,
    float* __restrict__ T)
{
    const int t = threadIdx.x;
    const int tx = t & 15, ty = t >> 4;
    const int b = blockIdx.x;
    const int n0 = blockIdx.y * 256;

    __shared__ float Pl[128][36];   // expB rows [i][k], row-major along n
    __shared__ float Ql[128][36];   // x rows [c][k]

    float acc[8][8];
#pragma unroll
    for (int i = 0; i < 8; ++i)
#pragma unroll
        for (int j = 0; j < 8; ++j) acc[i][j] = 0.f;

    const unsigned short* pB = expE + (size_t)b * R_ * HW_;   // rows 0..127 = expB
    const float* xb = x + (size_t)b * C_ * HW_;

    for (int ks = 0; ks < 256; ks += 32) {
        __syncthreads();
#pragma unroll
        for (int it = 0; it < 2; ++it) {
            int idx = it * 256 + t;
            int i = idx >> 2, ko = (idx & 3) << 3;
            uint4 v = *(const uint4*)&pB[(size_t)i * HW_ + n0 + ks + ko];
            float f[8]; unpack8(v, f);
            *(float4*)&Pl[i][ko]     = make_float4(f[0], f[1], f[2], f[3]);
            *(float4*)&Pl[i][ko + 4] = make_float4(f[4], f[5], f[6], f[7]);
        }
#pragma unroll
        for (int it = 0; it < 4; ++it) {
            int idx = it * 256 + t;
            int c = idx >> 3, kq = (idx & 7) << 2;
            *(float4*)&Ql[c][kq] = *(const float4*)&xb[(size_t)c * HW_ + n0 + ks + kq];
        }
        __syncthreads();
#pragma unroll
        for (int k = 0; k < 32; k += 4) {
            float4 pv[8], qv[8];
#pragma unroll
            for (int ii = 0; ii < 8; ++ii) pv[ii] = *(const float4*)&Pl[ii * 16 + ty][k];
#pragma unroll
            for (int cc = 0; cc < 8; ++cc) qv[cc] = *(const float4*)&Ql[cc * 16 + tx][k];
#pragma unroll
            for (int ii = 0; ii < 8; ++ii)
#pragma unroll
                for (int cc = 0; cc < 8; ++cc) {
                    acc[ii][cc] = fmaf(pv[ii].x, qv[cc].x, acc[ii][cc]);
                    acc[ii][cc] = fmaf(pv[ii].y, qv[cc].y, acc[ii][cc]);
                    acc[ii][cc] = fmaf(pv[ii].z, qv[cc].z, acc[ii][cc]);
                    acc[ii][cc] = fmaf(pv[ii].w, qv[cc].w, acc[ii][cc]);
                }
        }
    }
#pragma unroll
    for (int ii = 0; ii < 8; ++ii)
#pragma unroll
        for (int cc = 0; cc < 8; ++cc)
            atomicAdd(&T[((size_t)b * 128 + ii * 16 + ty) * 128 + cc * 16 + tx], acc[ii][cc]);
}

// K3b: G[b,i,j] = (dot(T[b,i,:], wA[j,:]) / ZB_i + bA[j]) / (4096 * ZV_i)
// grid (4 tiles, 32 b), block 256. Tile 64i x 64j.
__global__ __launch_bounds__(256) void k3b_G(
    const float* __restrict__ T, const float* __restrict__ wA, const float* __restrict__ bA,
    const float* __restrict__ Zcat, float* __restrict__ G)
{
    const int t = threadIdx.x;
    const int tx = t & 15, ty = t >> 4;
    const int b = blockIdx.y;
    const int ib = (blockIdx.x >> 1) * 64;
    const int jb = (blockIdx.x & 1) * 64;

    __shared__ float Ts[64][36];
    __shared__ float Wa[64][36];

    float acc[4][4];
#pragma unroll
    for (int i = 0; i < 4; ++i)
#pragma unroll
        for (int j = 0; j < 4; ++j) acc[i][j] = 0.f;

    for (int c0 = 0; c0 < 128; c0 += 32) {
        __syncthreads();
#pragma unroll
        for (int it = 0; it < 2; ++it) {
            int idx = it * 256 + t;
            int r = idx >> 3, kq = (idx & 7) << 2;
            *(float4*)&Ts[r][kq] = *(const float4*)&T[((size_t)b * 128 + ib + r) * 128 + c0 + kq];
        }
#pragma unroll
        for (int it = 0; it < 2; ++it) {
            int idx = it * 256 + t;
            int r = idx >> 3, kq = (idx & 7) << 2;
            *(float4*)&Wa[r][kq] = *(const float4*)&wA[(jb + r) * 128 + c0 + kq];
        }
        __syncthreads();
#pragma unroll
        for (int k = 0; k < 32; k += 4) {
            float4 tv[4], wv[4];
#pragma unroll
            for (int ii = 0; ii < 4; ++ii) tv[ii] = *(const float4*)&Ts[ii * 16 + ty][k];
#pragma unroll
            for (int jj = 0; jj < 4; ++jj) wv[jj] = *(const float4*)&Wa[jj * 16 + tx][k];
#pragma unroll
            for (int ii = 0; ii < 4; ++ii)
#pragma unroll
                for (int jj = 0; jj < 4; ++jj) {
                    acc[ii][jj] = fmaf(tv[ii].x, wv[jj].x, acc[ii][jj]);
                    acc[ii][jj] = fmaf(tv[ii].y, wv[jj].y, acc[ii][jj]);
                    acc[ii][jj] = fmaf(tv[ii].z, wv[jj].z, acc[ii][jj]);
                    acc[ii][jj] = fmaf(tv[ii].w, wv[jj].w, acc[ii][jj]);
                }
        }
    }
    const float* ZB = Zcat + b * R_;
    const float* ZV = ZB + 128;
#pragma unroll
    for (int ii = 0; ii < 4; ++ii) {
        int i = ib + ii * 16 + ty;
        float rzb = 1.f / ZB[i];
        float s = 1.f / (4096.f * ZV[i]);
#pragma unroll
        for (int jj = 0; jj < 4; ++jj) {
            int j = jb + jj * 16 + tx;
            G[((size_t)b * 128 + i) * 128 + j] = (acc[ii][jj] * rzb + bA[j]) * s;
        }
    }
}

// K4: out[b,j,n] = sum_i expV[b,i,n] * G[b,i,j].
// grid (32 ntiles, 32 b), block 256. Tile 128j x 128n, K=128 (i).
__global__ __launch_bounds__(256) void k4_out(
    const unsigned short* __restrict__ expE, const float* __restrict__ G,
    float* __restrict__ out)
{
    const int t = threadIdx.x;
    const int tx = t & 15, ty = t >> 4;
    const int b = blockIdx.y;
    const int nb = blockIdx.x * 128;

    __shared__ float Gl[32][132];   // [k=i][j]
    __shared__ float Vl[32][132];   // [k=i][n]

    float acc[8][8];
#pragma unroll
    for (int i = 0; i < 8; ++i)
#pragma unroll
        for (int j = 0; j < 8; ++j) acc[i][j] = 0.f;

    const unsigned short* pV = expE + ((size_t)b * R_ + 128) * HW_;
    const float* Gb = G + (size_t)b * 128 * 128;

    for (int ks = 0; ks < 128; ks += 32) {
        __syncthreads();
#pragma unroll
        for (int it = 0; it < 4; ++it) {
            int idx = it * 256 + t;
            int k = idx >> 5, jq = (idx & 31) << 2;
            *(float4*)&Gl[k][jq] = *(const float4*)&Gb[(size_t)(ks + k) * 128 + jq];
        }
#pragma unroll
        for (int it = 0; it < 2; ++it) {
            int idx = it * 256 + t;
            int k = idx >> 4, no = (idx & 15) << 3;
            uint4 v = *(const uint4*)&pV[(size_t)(ks + k) * HW_ + nb + no];
            float f[8]; unpack8(v, f);
            *(float4*)&Vl[k][no]     = make_float4(f[0], f[1], f[2], f[3]);
            *(float4*)&Vl[k][no + 4] = make_float4(f[4], f[5], f[6], f[7]);
        }
        __syncthreads();
#pragma unroll
        for (int k = 0; k < 32; ++k) {
            float4 ga = *(const float4*)&Gl[k][ty * 8];
            float4 gc = *(const float4*)&Gl[k][ty * 8 + 4];
            float4 va = *(const float4*)&Vl[k][tx * 8];
            float4 vc = *(const float4*)&Vl[k][tx * 8 + 4];
            float g[8] = {ga.x, ga.y, ga.z, ga.w, gc.x, gc.y, gc.z, gc.w};
            float v[8] = {va.x, va.y, va.z, va.w, vc.x, vc.y, vc.z, vc.w};
#pragma unroll
            for (int jj = 0; jj < 8; ++jj)
#pragma unroll
                for (int nn = 0; nn < 8; ++nn)
                    acc[jj][nn] = fmaf(g[jj], v[nn], acc[jj][nn]);
        }
    }
    float* ob = out + (size_t)b * C_ * HW_;
#pragma unroll
    for (int jj = 0; jj < 8; ++jj) {
        int j = ty * 8 + jj;
        *(float4*)&ob[(size_t)j * HW_ + nb + tx * 8]     = make_float4(acc[jj][0], acc[jj][1], acc[jj][2], acc[jj][3]);
        *(float4*)&ob[(size_t)j * HW_ + nb + tx * 8 + 4] = make_float4(acc[jj][4], acc[jj][5], acc[jj][6], acc[jj][7]);
    }
}

extern "C" void kernel_launch(void* const* d_in, const int* in_sizes, int n_in,
                              void* d_out, int out_size, void* d_ws, size_t ws_size,
                              hipStream_t stream)
{
    const float* x  = (const float*)d_in[0];
    const float* wA = (const float*)d_in[1];
    const float* bA = (const float*)d_in[2];
    const float* wB = (const float*)d_in[3];
    const float* bB = (const float*)d_in[4];
    const float* wV = (const float*)d_in[5];
    const float* bV = (const float*)d_in[6];
    float* out = (float*)d_out;

    // workspace layout (68.2 MiB total):
    //   Zcat  : 32*256 f32                (32 KiB)  -- rows 0..127 ZB, 128..255 ZV
    //   T     : 32*128*128 f32            (2 MiB)   -- atomic-accumulated
    //   G     : 32*128*128 f32            (2 MiB)
    //   expE  : 32*256*4096 bf16          (64 MiB)  -- exp(B) rows 0..127, exp(V) rows 128..255
    char* ws = (char*)d_ws;
    float* Zcat = (float*)ws;
    float* T    = (float*)(ws + 32768);
    float* G    = (float*)(ws + 32768 + 2097152);
    unsigned short* expE = (unsigned short*)(ws + 32768 + 2097152 + 2097152);

    hipMemsetAsync(Zcat, 0, 32768 + 2097152, stream);   // zero Zcat + T

    k1_bv <<<dim3(32, 4, 32), 256, 0, stream>>>(x, wB, bB, wV, bV, expE, Zcat);
    k3_T  <<<dim3(32, 16),    256, 0, stream>>>(expE, x, T);
    k3b_G <<<dim3(4, 32),     256, 0, stream>>>(T, wA, bA, Zcat, G);
    k4_out<<<dim3(32, 32),    256, 0, stream>>>(expE, G, out);
}

// Round 2
// 338.682 us; speedup vs baseline: 1.0215x; 1.0215x over previous
//
#include <hip/hip_runtime.h>
#include <hip/hip_bf16.h>

// Problem: B=32, C=128, HW=64*64=4096.
// out[b,j,n] = sum_i softmax_n(V)[i,n] * gd[i,j]
// gd[i,j]    = (1/hw) * sum_n softmax_n(B)[i,n] * A[j,n]
// Restructure: A eliminated via T[i,c] = sum_n expB[i,n]*x[c,n]:
//   gd[i,j] = (T[i,:]/ZB_i . wA[j,:] + bA[j]) / hw
//   G[i,j]  = gd[i,j] / ZV_i ;  out[j,n] = sum_i expV[i,n] * G[i,j]

#define B_  32
#define C_  128
#define HW_ 4096
#define R_  256   // 2*C rows (B-proj rows 0..127, V-proj rows 128..255)

__device__ __forceinline__ unsigned short f2bf(float f) {
    unsigned int u = __float_as_uint(f);
    u += 0x7fffu + ((u >> 16) & 1u);          // RNE to bf16
    return (unsigned short)(u >> 16);
}

__device__ __forceinline__ void unpack8(uint4 v, float* o) {
    o[0] = __uint_as_float(v.x << 16); o[1] = __uint_as_float(v.x & 0xffff0000u);
    o[2] = __uint_as_float(v.y << 16); o[3] = __uint_as_float(v.y & 0xffff0000u);
    o[4] = __uint_as_float(v.z << 16); o[5] = __uint_as_float(v.z & 0xffff0000u);
    o[6] = __uint_as_float(v.w << 16); o[7] = __uint_as_float(v.w & 0xffff0000u);
}

__device__ __forceinline__ void unpack4(uint2 v, float* o) {
    o[0] = __uint_as_float(v.x << 16); o[1] = __uint_as_float(v.x & 0xffff0000u);
    o[2] = __uint_as_float(v.y << 16); o[3] = __uint_as_float(v.y & 0xffff0000u);
}

// K1: E = [wB;wV] @ x + bias ; store exp(E) as bf16 ; row sums of exp -> Zcat.
// grid (32 ntiles, 2 rowtiles, 32 b), block 256. Tile 128 rows x 128 n, K=128.
// 8x8 acc/thread; thread cols {tx*4, 64+tx*4} (stride-4 -> 2-way LDS = free).
__global__ __launch_bounds__(256) void k1_bv(
    const float* __restrict__ x, const float* __restrict__ wB, const float* __restrict__ bB,
    const float* __restrict__ wV, const float* __restrict__ bV,
    unsigned short* __restrict__ expE, float* __restrict__ Zcat)
{
    const int t = threadIdx.x;
    const int tx = t & 15, ty = t >> 4;
    const int b = blockIdx.z;
    const int rowTile = blockIdx.y;          // 0 -> B proj, 1 -> V proj
    const int nb = blockIdx.x * 128;

    const float* wSrc = (rowTile == 0) ? wB : wV;
    const float* bSrc = (rowTile == 0) ? bB : bV;
    const int gRowBase = rowTile * 128;

    __shared__ float Wl[128][36];   // [row][k], pad 36
    __shared__ float Xl[32][132];   // [k][n],  pad 132

    float acc[8][8];
#pragma unroll
    for (int i = 0; i < 8; ++i)
#pragma unroll
        for (int j = 0; j < 8; ++j) acc[i][j] = 0.f;

    const float* xb = x + (size_t)b * C_ * HW_;

    for (int k0 = 0; k0 < 128; k0 += 32) {
        __syncthreads();
#pragma unroll
        for (int it = 0; it < 4; ++it) {
            int idx = it * 256 + t;
            int row = idx >> 3, kq = (idx & 7) << 2;
            *(float4*)&Wl[row][kq] = *(const float4*)&wSrc[row * 128 + k0 + kq];
        }
#pragma unroll
        for (int it = 0; it < 4; ++it) {
            int idx = it * 256 + t;
            int k = idx >> 5, nq = (idx & 31) << 2;
            *(float4*)&Xl[k][nq] = *(const float4*)&xb[(size_t)(k0 + k) * HW_ + nb + nq];
        }
        __syncthreads();
#pragma unroll
        for (int k = 0; k < 32; k += 4) {
            float wr[8][4];
#pragma unroll
            for (int rr = 0; rr < 8; ++rr) {
                float4 wv = *(const float4*)&Wl[rr * 16 + ty][k];
                wr[rr][0] = wv.x; wr[rr][1] = wv.y; wr[rr][2] = wv.z; wr[rr][3] = wv.w;
            }
#pragma unroll
            for (int d = 0; d < 4; ++d) {
                float4 xa = *(const float4*)&Xl[k + d][tx * 4];
                float4 xc = *(const float4*)&Xl[k + d][64 + tx * 4];
                float xs[8] = {xa.x, xa.y, xa.z, xa.w, xc.x, xc.y, xc.z, xc.w};
#pragma unroll
                for (int rr = 0; rr < 8; ++rr)
#pragma unroll
                    for (int nn = 0; nn < 8; ++nn)
                        acc[rr][nn] = fmaf(wr[rr][d], xs[nn], acc[rr][nn]);
            }
        }
    }

#pragma unroll
    for (int rr = 0; rr < 8; ++rr) {
        int lr = rr * 16 + ty;              // 0..127
        int gr = gRowBase + lr;             // 0..255
        float bias = bSrc[lr];
        float e[8]; float rs = 0.f;
#pragma unroll
        for (int nn = 0; nn < 8; ++nn) { e[nn] = __expf(acc[rr][nn] + bias); rs += e[nn]; }
        // cols: e[0..3] -> nb+tx*4, e[4..7] -> nb+64+tx*4
        unsigned int p0 = (unsigned int)f2bf(e[0]) | ((unsigned int)f2bf(e[1]) << 16);
        unsigned int p1 = (unsigned int)f2bf(e[2]) | ((unsigned int)f2bf(e[3]) << 16);
        unsigned int p2 = (unsigned int)f2bf(e[4]) | ((unsigned int)f2bf(e[5]) << 16);
        unsigned int p3 = (unsigned int)f2bf(e[6]) | ((unsigned int)f2bf(e[7]) << 16);
        size_t rbase = ((size_t)b * R_ + gr) * HW_ + nb;
        *(uint2*)&expE[rbase + tx * 4]      = make_uint2(p0, p1);
        *(uint2*)&expE[rbase + 64 + tx * 4] = make_uint2(p2, p3);
        rs += __shfl_down(rs, 8, 16);
        rs += __shfl_down(rs, 4, 16);
        rs += __shfl_down(rs, 2, 16);
        rs += __shfl_down(rs, 1, 16);
        if (tx == 0) atomicAdd(&Zcat[b * R_ + gr], rs);
    }
}

// K3: T[b,i,c] += sum_{n in chunk} expB[b,i,n] * x[b,c,n].
// grid (32 b, 16 chunks of 256), block 256. Tile 128i x 128c, 8x8/thread.
__global__ __launch_bounds__(256) void k3_T(
    const unsigned short* __restrict__ expE, const float* __restrict__ x,
    float* __restrict__ T)
{
    const int t = threadIdx.x;
    const int tx = t & 15, ty = t >> 4;
    const int b = blockIdx.x;
    const int n0 = blockIdx.y * 256;

    __shared__ float Pl[128][36];   // expB rows [i][k]
    __shared__ float Ql[128][36];   // x rows [c][k]

    float acc[8][8];
#pragma unroll
    for (int i = 0; i < 8; ++i)
#pragma unroll
        for (int j = 0; j < 8; ++j) acc[i][j] = 0.f;

    const unsigned short* pB = expE + (size_t)b * R_ * HW_;   // rows 0..127 = expB
    const float* xb = x + (size_t)b * C_ * HW_;

    for (int ks = 0; ks < 256; ks += 32) {
        __syncthreads();
#pragma unroll
        for (int it = 0; it < 2; ++it) {
            int idx = it * 256 + t;
            int i = idx >> 2, ko = (idx & 3) << 3;
            uint4 v = *(const uint4*)&pB[(size_t)i * HW_ + n0 + ks + ko];
            float f[8]; unpack8(v, f);
            *(float4*)&Pl[i][ko]     = make_float4(f[0], f[1], f[2], f[3]);
            *(float4*)&Pl[i][ko + 4] = make_float4(f[4], f[5], f[6], f[7]);
        }
#pragma unroll
        for (int it = 0; it < 4; ++it) {
            int idx = it * 256 + t;
            int c = idx >> 3, kq = (idx & 7) << 2;
            *(float4*)&Ql[c][kq] = *(const float4*)&xb[(size_t)c * HW_ + n0 + ks + kq];
        }
        __syncthreads();
#pragma unroll
        for (int k = 0; k < 32; k += 4) {
            float4 pv[8], qv[8];
#pragma unroll
            for (int ii = 0; ii < 8; ++ii) pv[ii] = *(const float4*)&Pl[ii * 16 + ty][k];
#pragma unroll
            for (int cc = 0; cc < 8; ++cc) qv[cc] = *(const float4*)&Ql[cc * 16 + tx][k];
#pragma unroll
            for (int ii = 0; ii < 8; ++ii)
#pragma unroll
                for (int cc = 0; cc < 8; ++cc) {
                    acc[ii][cc] = fmaf(pv[ii].x, qv[cc].x, acc[ii][cc]);
                    acc[ii][cc] = fmaf(pv[ii].y, qv[cc].y, acc[ii][cc]);
                    acc[ii][cc] = fmaf(pv[ii].z, qv[cc].z, acc[ii][cc]);
                    acc[ii][cc] = fmaf(pv[ii].w, qv[cc].w, acc[ii][cc]);
                }
        }
    }
#pragma unroll
    for (int ii = 0; ii < 8; ++ii)
#pragma unroll
        for (int cc = 0; cc < 8; ++cc)
            atomicAdd(&T[((size_t)b * 128 + ii * 16 + ty) * 128 + cc * 16 + tx], acc[ii][cc]);
}

// K3b: G[b,i,j] = (dot(T[b,i,:], wA[j,:]) / ZB_i + bA[j]) / (4096 * ZV_i)
// grid (4 tiles, 32 b), block 256. Tile 64i x 64j.
__global__ __launch_bounds__(256) void k3b_G(
    const float* __restrict__ T, const float* __restrict__ wA, const float* __restrict__ bA,
    const float* __restrict__ Zcat, float* __restrict__ G)
{
    const int t = threadIdx.x;
    const int tx = t & 15, ty = t >> 4;
    const int b = blockIdx.y;
    const int ib = (blockIdx.x >> 1) * 64;
    const int jb = (blockIdx.x & 1) * 64;

    __shared__ float Ts[64][36];
    __shared__ float Wa[64][36];

    float acc[4][4];
#pragma unroll
    for (int i = 0; i < 4; ++i)
#pragma unroll
        for (int j = 0; j < 4; ++j) acc[i][j] = 0.f;

    for (int c0 = 0; c0 < 128; c0 += 32) {
        __syncthreads();
#pragma unroll
        for (int it = 0; it < 2; ++it) {
            int idx = it * 256 + t;
            int r = idx >> 3, kq = (idx & 7) << 2;
            *(float4*)&Ts[r][kq] = *(const float4*)&T[((size_t)b * 128 + ib + r) * 128 + c0 + kq];
        }
#pragma unroll
        for (int it = 0; it < 2; ++it) {
            int idx = it * 256 + t;
            int r = idx >> 3, kq = (idx & 7) << 2;
            *(float4*)&Wa[r][kq] = *(const float4*)&wA[(jb + r) * 128 + c0 + kq];
        }
        __syncthreads();
#pragma unroll
        for (int k = 0; k < 32; k += 4) {
            float4 tv[4], wv[4];
#pragma unroll
            for (int ii = 0; ii < 4; ++ii) tv[ii] = *(const float4*)&Ts[ii * 16 + ty][k];
#pragma unroll
            for (int jj = 0; jj < 4; ++jj) wv[jj] = *(const float4*)&Wa[jj * 16 + tx][k];
#pragma unroll
            for (int ii = 0; ii < 4; ++ii)
#pragma unroll
                for (int jj = 0; jj < 4; ++jj) {
                    acc[ii][jj] = fmaf(tv[ii].x, wv[jj].x, acc[ii][jj]);
                    acc[ii][jj] = fmaf(tv[ii].y, wv[jj].y, acc[ii][jj]);
                    acc[ii][jj] = fmaf(tv[ii].z, wv[jj].z, acc[ii][jj]);
                    acc[ii][jj] = fmaf(tv[ii].w, wv[jj].w, acc[ii][jj]);
                }
        }
    }
    const float* ZB = Zcat + b * R_;
    const float* ZV = ZB + 128;
#pragma unroll
    for (int ii = 0; ii < 4; ++ii) {
        int i = ib + ii * 16 + ty;
        float rzb = 1.f / ZB[i];
        float s = 1.f / (4096.f * ZV[i]);
#pragma unroll
        for (int jj = 0; jj < 4; ++jj) {
            int j = jb + jj * 16 + tx;
            G[((size_t)b * 128 + i) * 128 + j] = (acc[ii][jj] * rzb + bA[j]) * s;
        }
    }
}

// K4: out[b,j,n] = sum_i expV[b,i,n] * G[b,i,j].
// grid (32 ntiles, 32 b), block 256. Tile 128j x 128n, K=128 (i).
// thread cols {tx*4, 64+tx*4}; rows j = ty*8+jj.
__global__ __launch_bounds__(256) void k4_out(
    const unsigned short* __restrict__ expE, const float* __restrict__ G,
    float* __restrict__ out)
{
    const int t = threadIdx.x;
    const int tx = t & 15, ty = t >> 4;
    const int b = blockIdx.y;
    const int nb = blockIdx.x * 128;

    __shared__ float Gl[32][132];   // [k=i][j]
    __shared__ float Vl[32][132];   // [k=i][n]

    float acc[8][8];
#pragma unroll
    for (int i = 0; i < 8; ++i)
#pragma unroll
        for (int j = 0; j < 8; ++j) acc[i][j] = 0.f;

    const unsigned short* pV = expE + ((size_t)b * R_ + 128) * HW_;
    const float* Gb = G + (size_t)b * 128 * 128;

    for (int ks = 0; ks < 128; ks += 32) {
        __syncthreads();
#pragma unroll
        for (int it = 0; it < 4; ++it) {
            int idx = it * 256 + t;
            int k = idx >> 5, jq = (idx & 31) << 2;
            *(float4*)&Gl[k][jq] = *(const float4*)&Gb[(size_t)(ks + k) * 128 + jq];
        }
        // expV staging: each lane unpacks 4 bf16 (uint2) -> stride-4 writes (2-way, free)
#pragma unroll
        for (int it = 0; it < 4; ++it) {
            int idx = it * 256 + t;
            int k = idx >> 5, no = (idx & 31) << 2;
            uint2 v = *(const uint2*)&pV[(size_t)(ks + k) * HW_ + nb + no];
            float f[4]; unpack4(v, f);
            *(float4*)&Vl[k][no] = make_float4(f[0], f[1], f[2], f[3]);
        }
        __syncthreads();
#pragma unroll
        for (int k = 0; k < 32; ++k) {
            float4 ga = *(const float4*)&Gl[k][ty * 8];
            float4 gc = *(const float4*)&Gl[k][ty * 8 + 4];
            float4 va = *(const float4*)&Vl[k][tx * 4];
            float4 vc = *(const float4*)&Vl[k][64 + tx * 4];
            float g[8] = {ga.x, ga.y, ga.z, ga.w, gc.x, gc.y, gc.z, gc.w};
            float v[8] = {va.x, va.y, va.z, va.w, vc.x, vc.y, vc.z, vc.w};
#pragma unroll
            for (int jj = 0; jj < 8; ++jj)
#pragma unroll
                for (int nn = 0; nn < 8; ++nn)
                    acc[jj][nn] = fmaf(g[jj], v[nn], acc[jj][nn]);
        }
    }
    float* ob = out + (size_t)b * C_ * HW_;
#pragma unroll
    for (int jj = 0; jj < 8; ++jj) {
        int j = ty * 8 + jj;
        *(float4*)&ob[(size_t)j * HW_ + nb + tx * 4]      = make_float4(acc[jj][0], acc[jj][1], acc[jj][2], acc[jj][3]);
        *(float4*)&ob[(size_t)j * HW_ + nb + 64 + tx * 4] = make_float4(acc[jj][4], acc[jj][5], acc[jj][6], acc[jj][7]);
    }
}

extern "C" void kernel_launch(void* const* d_in, const int* in_sizes, int n_in,
                              void* d_out, int out_size, void* d_ws, size_t ws_size,
                              hipStream_t stream)
{
    const float* x  = (const float*)d_in[0];
    const float* wA = (const float*)d_in[1];
    const float* bA = (const float*)d_in[2];
    const float* wB = (const float*)d_in[3];
    const float* bB = (const float*)d_in[4];
    const float* wV = (const float*)d_in[5];
    const float* bV = (const float*)d_in[6];
    float* out = (float*)d_out;

    // workspace layout (68.2 MiB total):
    //   Zcat  : 32*256 f32                (32 KiB)  -- rows 0..127 ZB, 128..255 ZV
    //   T     : 32*128*128 f32            (2 MiB)   -- atomic-accumulated
    //   G     : 32*128*128 f32            (2 MiB)
    //   expE  : 32*256*4096 bf16          (64 MiB)  -- exp(B) rows 0..127, exp(V) rows 128..255
    char* ws = (char*)d_ws;
    float* Zcat = (float*)ws;
    float* T    = (float*)(ws + 32768);
    float* G    = (float*)(ws + 32768 + 2097152);
    unsigned short* expE = (unsigned short*)(ws + 32768 + 2097152 + 2097152);

    hipMemsetAsync(Zcat, 0, 32768 + 2097152, stream);   // zero Zcat + T

    k1_bv <<<dim3(32, 2, 32), 256, 0, stream>>>(x, wB, bB, wV, bV, expE, Zcat);
    k3_T  <<<dim3(32, 16),    256, 0, stream>>>(expE, x, T);
    k3b_G <<<dim3(4, 32),     256, 0, stream>>>(T, wA, bA, Zcat, G);
    k4_out<<<dim3(32, 32),    256, 0, stream>>>(expE, G, out);
}

// Round 3
// 304.407 us; speedup vs baseline: 1.1365x; 1.1126x over previous
//
#include <hip/hip_runtime.h>
#include <hip/hip_bf16.h>

// B=32, C=128, HW=4096.
// Restructure (validated rounds 1-2):
//   E = [wB;wV]@x + bias ; expB/expV = exp(E) (bf16) ; ZB/ZV row sums (fp32)
//   T[i,c] = sum_n expB[i,n]*x[c,n]
//   G[i,j] = ((T[i,:].wA[j,:])/ZB_i + bA[j]) / (4096*ZV_i)
//   out[j,n] = sum_i expV[i,n]*G[i,j]
// This round: all three big GEMMs on MFMA (16x16x32 bf16) with hi/lo fp32
// splitting. expV stored transposed [n][i] so k4 is transpose-free; G stored
// transposed + pre-split (3 bf16 terms, residual 2^-27 => fp32-grade).

#define B_  32
#define C_  128
#define HW_ 4096

typedef __attribute__((ext_vector_type(8))) __bf16 bf16x8;
typedef __attribute__((ext_vector_type(4))) float f32x4;

__device__ __forceinline__ unsigned int bf_rne(float f) {   // bf16 bits (RNE)
    unsigned int u = __float_as_uint(f);
    return (u + 0x7fffu + ((u >> 16) & 1u)) >> 16;
}
__device__ __forceinline__ float bf_hi(float f) {           // RNE-to-bf16, as fp32
    unsigned int u = __float_as_uint(f);
    return __uint_as_float((u + 0x7fffu + ((u >> 16) & 1u)) & 0xffff0000u);
}

// ---------------------------------------------------------------------------
// k0: split Wcat=[wB;wV] (256x128 fp32) into bf16 hi/lo arrays. grid 32x256.
__global__ __launch_bounds__(256) void k0_prep(
    const float* __restrict__ wB, const float* __restrict__ wV,
    unsigned short* __restrict__ Wh, unsigned short* __restrict__ Wl)
{
    int g = blockIdx.x * 256 + threadIdx.x;      // 0..8191 float4s
    int row = g >> 5, c4 = (g & 31) << 2;
    const float* src = (row < 128) ? &wB[row * 128] : &wV[(row - 128) * 128];
    float4 v = *(const float4*)&src[c4];
    float vv[4] = {v.x, v.y, v.z, v.w};
    unsigned int h[4], l[4];
#pragma unroll
    for (int e = 0; e < 4; ++e) {
        float hf = bf_hi(vv[e]);
        h[e] = __float_as_uint(hf) >> 16;
        l[e] = bf_rne(vv[e] - hf);
    }
    *(uint2*)&Wh[row * 128 + c4] = make_uint2(h[0] | (h[1] << 16), h[2] | (h[3] << 16));
    *(uint2*)&Wl[row * 128 + c4] = make_uint2(l[0] | (l[1] << 16), l[2] | (l[3] << 16));
}

// ---------------------------------------------------------------------------
// k1: E-GEMM (MFMA, 3-term split) + exp + Z + store expB [i][n] / expVT [n][i].
// grid (64 ntiles, 32 b), block 256 = 4 waves. Block tile: 256 rows x 64 n.
__global__ __launch_bounds__(256) void k1_bv(
    const float* __restrict__ x,
    const unsigned short* __restrict__ Wh, const unsigned short* __restrict__ Wl,
    const float* __restrict__ bB, const float* __restrict__ bV,
    unsigned short* __restrict__ expB, unsigned short* __restrict__ expVT,
    float* __restrict__ Zcat)
{
    __shared__ unsigned short Xh[64 * 136];   // [n][c] pitch 136 (hi)
    __shared__ unsigned short Xl[64 * 136];   // [n][c] pitch 136 (lo)

    const int t = threadIdx.x;
    const int lane = t & 63, w = t >> 6;
    const int col16 = lane & 15, quad = lane >> 4;
    const int b = blockIdx.y, nb = blockIdx.x * 64;
    const float* xb = x + (size_t)b * C_ * HW_;

    // stage x tile transposed: global [c][n] fp32 -> LDS [n][c] bf16 hi/lo
    {
        int ng = t & 15, cb = t >> 4;
#pragma unroll
        for (int p = 0; p < 8; ++p) {
            int c = cb + p * 16;
            float4 v = *(const float4*)(xb + (size_t)c * HW_ + nb + ng * 4);
            float vv[4] = {v.x, v.y, v.z, v.w};
#pragma unroll
            for (int e = 0; e < 4; ++e) {
                float hf = bf_hi(vv[e]);
                int n = ng * 4 + e;
                Xh[n * 136 + c] = (unsigned short)(__float_as_uint(hf) >> 16);
                Xl[n * 136 + c] = (unsigned short)bf_rne(vv[e] - hf);
            }
        }
    }
    __syncthreads();

    f32x4 acc[4][4];
#pragma unroll
    for (int i = 0; i < 4; ++i)
#pragma unroll
        for (int j = 0; j < 4; ++j) acc[i][j] = (f32x4){0.f, 0.f, 0.f, 0.f};

    const int rowbase = w * 64;   // global row range of this wave (0..255)
#pragma unroll
    for (int ks = 0; ks < 4; ++ks) {
        int kc = ks * 32 + quad * 8;
        bf16x8 wh[4], wl[4], xh[4], xl[4];
#pragma unroll
        for (int mt = 0; mt < 4; ++mt) {
            int row = rowbase + mt * 16 + col16;
            wh[mt] = *(const bf16x8*)&Wh[row * 128 + kc];
            wl[mt] = *(const bf16x8*)&Wl[row * 128 + kc];
        }
#pragma unroll
        for (int nt = 0; nt < 4; ++nt) {
            int n = nt * 16 + col16;
            xh[nt] = *(const bf16x8*)&Xh[n * 136 + kc];
            xl[nt] = *(const bf16x8*)&Xl[n * 136 + kc];
        }
#pragma unroll
        for (int mt = 0; mt < 4; ++mt)
#pragma unroll
            for (int nt = 0; nt < 4; ++nt) {
                acc[mt][nt] = __builtin_amdgcn_mfma_f32_16x16x32_bf16(wh[mt], xh[nt], acc[mt][nt], 0, 0, 0);
                acc[mt][nt] = __builtin_amdgcn_mfma_f32_16x16x32_bf16(wh[mt], xl[nt], acc[mt][nt], 0, 0, 0);
                acc[mt][nt] = __builtin_amdgcn_mfma_f32_16x16x32_bf16(wl[mt], xh[nt], acc[mt][nt], 0, 0, 0);
            }
    }
    __syncthreads();   // X dead; reuse LDS for epilogue staging

    unsigned short* ebS = Xh;   // [i(128)][n(64)] pitch 64
    unsigned short* evS = Xl;   // [n(64)][i(128)] pitch 136
    const float* bptr = (w < 2) ? bB : bV;
    const int wrow = (w & 1) * 64;       // row base within the 128-row proj
    const int zoff = (w < 2) ? 0 : 128;

#pragma unroll
    for (int mt = 0; mt < 4; ++mt) {
#pragma unroll
        for (int r = 0; r < 4; ++r) {
            int lrow = wrow + mt * 16 + quad * 4 + r;   // 0..127 within proj
            float bias = bptr[lrow];
            float rs = 0.f;
            unsigned short eb[4];
#pragma unroll
            for (int nt = 0; nt < 4; ++nt) {
                float e = __expf(acc[mt][nt][r] + bias);
                rs += e;
                eb[nt] = (unsigned short)bf_rne(e);
            }
            if (w < 2) {
#pragma unroll
                for (int nt = 0; nt < 4; ++nt)
                    ebS[lrow * 64 + nt * 16 + col16] = eb[nt];
            } else {
#pragma unroll
                for (int nt = 0; nt < 4; ++nt)
                    evS[(nt * 16 + col16) * 136 + lrow] = eb[nt];
            }
            rs += __shfl_xor(rs, 1, 16);
            rs += __shfl_xor(rs, 2, 16);
            rs += __shfl_xor(rs, 4, 16);
            rs += __shfl_xor(rs, 8, 16);
            if (col16 == 0) atomicAdd(&Zcat[b * 256 + zoff + lrow], rs);
        }
    }
    __syncthreads();

    // cooperative copy-out (bank-rotated LDS reads, coalesced global writes)
#pragma unroll
    for (int it = 0; it < 4; ++it) {
        int idx = it * 256 + t;               // 0..1023
        int row = idx >> 3, o = idx & 7;
        int o2 = (o + row) & 7;
        *(uint4*)&expB[((size_t)b * 128 + row) * HW_ + nb + o2 * 8] =
            *(const uint4*)&ebS[row * 64 + o2 * 8];
    }
#pragma unroll
    for (int it = 0; it < 4; ++it) {
        int idx = it * 256 + t;               // 0..1023
        int n = idx >> 4, o = idx & 15;
        int o2 = (o + 4 * (n & 3)) & 15;
        *(uint4*)&expVT[((size_t)b * HW_ + nb + n) * 128 + o2 * 8] =
            *(const uint4*)&evS[n * 136 + o2 * 8];
    }
}

// ---------------------------------------------------------------------------
// k3: T[b,i,c] += sum_n expB[i,n]*(xh+xl)[c,n]  (MFMA, transpose-free).
// grid (16 nchunks, 32 b), block 256. Block: M=128 i x N=128 c, K=256 n.
__global__ __launch_bounds__(256) void k3_T(
    const unsigned short* __restrict__ expB, const float* __restrict__ x,
    float* __restrict__ T)
{
    __shared__ unsigned short Xh[128 * 72];   // [c][n] pitch 72 (hi)
    __shared__ unsigned short Xl[128 * 72];   // [c][n] pitch 72 (lo)

    const int t = threadIdx.x;
    const int lane = t & 63, w = t >> 6;
    const int col16 = lane & 15, quad = lane >> 4;
    const int b = blockIdx.y, n0 = blockIdx.x * 256;
    const int mh = (w >> 1) * 64, nh = (w & 1) * 64;   // wave: 64 i x 64 c

    f32x4 acc[4][4];
#pragma unroll
    for (int i = 0; i < 4; ++i)
#pragma unroll
        for (int j = 0; j < 4; ++j) acc[i][j] = (f32x4){0.f, 0.f, 0.f, 0.f};

    const unsigned short* eb = expB + (size_t)b * 128 * HW_;
    const float* xb = x + (size_t)b * C_ * HW_;

    for (int st = 0; st < 4; ++st) {        // 4 stages of 64 n
        int ns = n0 + st * 64;
        __syncthreads();
        {   // stage x[c][ns..ns+64) -> bf16 hi/lo (natural layout, uint2 writes)
            int ng = t & 15, cb = t >> 4;
#pragma unroll
            for (int p = 0; p < 8; ++p) {
                int c = cb + p * 16;
                float4 v = *(const float4*)(xb + (size_t)c * HW_ + ns + ng * 4);
                float vv[4] = {v.x, v.y, v.z, v.w};
                unsigned int h[4], l[4];
#pragma unroll
                for (int e = 0; e < 4; ++e) {
                    float hf = bf_hi(vv[e]);
                    h[e] = __float_as_uint(hf) >> 16;
                    l[e] = bf_rne(vv[e] - hf);
                }
                *(uint2*)&Xh[c * 72 + ng * 4] = make_uint2(h[0] | (h[1] << 16), h[2] | (h[3] << 16));
                *(uint2*)&Xl[c * 72 + ng * 4] = make_uint2(l[0] | (l[1] << 16), l[2] | (l[3] << 16));
            }
        }
        __syncthreads();
#pragma unroll
        for (int ks = 0; ks < 2; ++ks) {
            int ko = ks * 32 + quad * 8;    // 0..63 within stage
            bf16x8 a[4], xh[4], xl[4];
#pragma unroll
            for (int mt = 0; mt < 4; ++mt)
                a[mt] = *(const bf16x8*)&eb[(size_t)(mh + mt * 16 + col16) * HW_ + ns + ko];
#pragma unroll
            for (int ct = 0; ct < 4; ++ct) {
                int c = nh + ct * 16 + col16;
                xh[ct] = *(const bf16x8*)&Xh[c * 72 + ko];
                xl[ct] = *(const bf16x8*)&Xl[c * 72 + ko];
            }
#pragma unroll
            for (int mt = 0; mt < 4; ++mt)
#pragma unroll
                for (int ct = 0; ct < 4; ++ct) {
                    acc[mt][ct] = __builtin_amdgcn_mfma_f32_16x16x32_bf16(a[mt], xh[ct], acc[mt][ct], 0, 0, 0);
                    acc[mt][ct] = __builtin_amdgcn_mfma_f32_16x16x32_bf16(a[mt], xl[ct], acc[mt][ct], 0, 0, 0);
                }
        }
    }
#pragma unroll
    for (int mt = 0; mt < 4; ++mt)
#pragma unroll
        for (int ct = 0; ct < 4; ++ct)
#pragma unroll
            for (int r = 0; r < 4; ++r) {
                int i = mh + mt * 16 + quad * 4 + r;
                int c = nh + ct * 16 + col16;
                atomicAdd(&T[((size_t)b * 128 + i) * 128 + c], acc[mt][ct][r]);
            }
}

// ---------------------------------------------------------------------------
// k3b: G transposed + 3-way bf16 split. grid (4, 32), block 256, fp32 VALU.
// acc[j][i] = sum_c wA[j][c]*T[i][c];  Gt*[j][i] = split((acc/ZB_i+bA[j])/(4096*ZV_i))
__global__ __launch_bounds__(256) void k3b_G(
    const float* __restrict__ T, const float* __restrict__ wA, const float* __restrict__ bA,
    const float* __restrict__ Zcat,
    unsigned short* __restrict__ Gth, unsigned short* __restrict__ Gtm,
    unsigned short* __restrict__ Gtl)
{
    const int t = threadIdx.x;
    const int tx = t & 15, ty = t >> 4;
    const int b = blockIdx.y;
    const int jb = (blockIdx.x >> 1) * 64;
    const int ib = (blockIdx.x & 1) * 64;

    __shared__ float Ts[64][36];   // T rows i
    __shared__ float Wa[64][36];   // wA rows j

    float acc[4][4];
#pragma unroll
    for (int i = 0; i < 4; ++i)
#pragma unroll
        for (int j = 0; j < 4; ++j) acc[i][j] = 0.f;

    for (int c0 = 0; c0 < 128; c0 += 32) {
        __syncthreads();
#pragma unroll
        for (int it = 0; it < 2; ++it) {
            int idx = it * 256 + t;
            int r = idx >> 3, kq = (idx & 7) << 2;
            *(float4*)&Ts[r][kq] = *(const float4*)&T[((size_t)b * 128 + ib + r) * 128 + c0 + kq];
        }
#pragma unroll
        for (int it = 0; it < 2; ++it) {
            int idx = it * 256 + t;
            int r = idx >> 3, kq = (idx & 7) << 2;
            *(float4*)&Wa[r][kq] = *(const float4*)&wA[(jb + r) * 128 + c0 + kq];
        }
        __syncthreads();
#pragma unroll
        for (int k = 0; k < 32; k += 4) {
            float4 wv[4], tv[4];
#pragma unroll
            for (int jj = 0; jj < 4; ++jj) wv[jj] = *(const float4*)&Wa[jj * 16 + ty][k];
#pragma unroll
            for (int ii = 0; ii < 4; ++ii) tv[ii] = *(const float4*)&Ts[ii * 16 + tx][k];
#pragma unroll
            for (int jj = 0; jj < 4; ++jj)
#pragma unroll
                for (int ii = 0; ii < 4; ++ii) {
                    acc[jj][ii] = fmaf(wv[jj].x, tv[ii].x, acc[jj][ii]);
                    acc[jj][ii] = fmaf(wv[jj].y, tv[ii].y, acc[jj][ii]);
                    acc[jj][ii] = fmaf(wv[jj].z, tv[ii].z, acc[jj][ii]);
                    acc[jj][ii] = fmaf(wv[jj].w, tv[ii].w, acc[jj][ii]);
                }
        }
    }
    const float* ZB = Zcat + b * 256;
    const float* ZV = ZB + 128;
#pragma unroll
    for (int jj = 0; jj < 4; ++jj) {
        int j = jb + jj * 16 + ty;
        float bj = bA[j];
#pragma unroll
        for (int ii = 0; ii < 4; ++ii) {
            int i = ib + ii * 16 + tx;
            float g = (acc[jj][ii] / ZB[i] + bj) / (4096.f * ZV[i]);
            float h = bf_hi(g);  float r1 = g - h;
            float m = bf_hi(r1); float r2 = r1 - m;
            size_t o = ((size_t)b * 128 + j) * 128 + i;
            Gth[o] = (unsigned short)(__float_as_uint(h) >> 16);
            Gtm[o] = (unsigned short)(__float_as_uint(m) >> 16);
            Gtl[o] = (unsigned short)bf_rne(r2);
        }
    }
}

// ---------------------------------------------------------------------------
// k4: out[b,j,n] = sum_i expVT[n][i] * Gt(j,i)  (MFMA, 3-term G split).
// grid (32 ntiles, 32 b), block 256. Block: M=128 j x N=128 n, K=128 i.
__global__ __launch_bounds__(256) void k4_out(
    const unsigned short* __restrict__ expVT,
    const unsigned short* __restrict__ Gth, const unsigned short* __restrict__ Gtm,
    const unsigned short* __restrict__ Gtl, float* __restrict__ out)
{
    __shared__ unsigned short Vs[128 * 136];   // [n][i] pitch 136

    const int t = threadIdx.x;
    const int lane = t & 63, w = t >> 6;
    const int col16 = lane & 15, quad = lane >> 4;
    const int b = blockIdx.y, nb = blockIdx.x * 128;

    // stage expVT tile (coalesced reads, bank-rotated writes)
#pragma unroll
    for (int it = 0; it < 8; ++it) {
        int idx = it * 256 + t;               // 0..2047
        int n = idx >> 4, o = idx & 15;
        int o2 = (o + 4 * (n & 3)) & 15;
        *(uint4*)&Vs[n * 136 + o2 * 8] =
            *(const uint4*)&expVT[((size_t)b * HW_ + nb + n) * 128 + o2 * 8];
    }
    __syncthreads();

    f32x4 acc[8][2];
#pragma unroll
    for (int i = 0; i < 8; ++i)
#pragma unroll
        for (int j = 0; j < 2; ++j) acc[i][j] = (f32x4){0.f, 0.f, 0.f, 0.f};

    const unsigned short* gh = Gth + (size_t)b * 128 * 128;
    const unsigned short* gm = Gtm + (size_t)b * 128 * 128;
    const unsigned short* gl = Gtl + (size_t)b * 128 * 128;

#pragma unroll
    for (int ks = 0; ks < 4; ++ks) {
        int ko = ks * 32 + quad * 8;
        bf16x8 vfr[2];
#pragma unroll
        for (int nt = 0; nt < 2; ++nt) {
            int n = w * 32 + nt * 16 + col16;
            vfr[nt] = *(const bf16x8*)&Vs[n * 136 + ko];
        }
#pragma unroll
        for (int mt = 0; mt < 8; ++mt) {
            int j = mt * 16 + col16;
            bf16x8 ah = *(const bf16x8*)&gh[j * 128 + ko];
            bf16x8 am = *(const bf16x8*)&gm[j * 128 + ko];
            bf16x8 al = *(const bf16x8*)&gl[j * 128 + ko];
#pragma unroll
            for (int nt = 0; nt < 2; ++nt) {
                acc[mt][nt] = __builtin_amdgcn_mfma_f32_16x16x32_bf16(ah, vfr[nt], acc[mt][nt], 0, 0, 0);
                acc[mt][nt] = __builtin_amdgcn_mfma_f32_16x16x32_bf16(am, vfr[nt], acc[mt][nt], 0, 0, 0);
                acc[mt][nt] = __builtin_amdgcn_mfma_f32_16x16x32_bf16(al, vfr[nt], acc[mt][nt], 0, 0, 0);
            }
        }
    }
    float* ob = out + (size_t)b * C_ * HW_;
#pragma unroll
    for (int mt = 0; mt < 8; ++mt)
#pragma unroll
        for (int nt = 0; nt < 2; ++nt)
#pragma unroll
            for (int r = 0; r < 4; ++r) {
                int j = mt * 16 + quad * 4 + r;
                int n = nb + w * 32 + nt * 16 + col16;
                ob[(size_t)j * HW_ + n] = acc[mt][nt][r];
            }
}

// ---------------------------------------------------------------------------
extern "C" void kernel_launch(void* const* d_in, const int* in_sizes, int n_in,
                              void* d_out, int out_size, void* d_ws, size_t ws_size,
                              hipStream_t stream)
{
    const float* x  = (const float*)d_in[0];
    const float* wA = (const float*)d_in[1];
    const float* bA = (const float*)d_in[2];
    const float* wB = (const float*)d_in[3];
    const float* bB = (const float*)d_in[4];
    const float* wV = (const float*)d_in[5];
    const float* bV = (const float*)d_in[6];
    float* out = (float*)d_out;

    // workspace (66.2 MiB):
    //   Zcat 32 KiB | T 2 MiB | Wh 64 KiB | Wl 64 KiB | expB 32 MiB | expVT 32 MiB
    //   Gth/Gtm/Gtl (3 MiB) alias the expB region (expB dead after k3).
    char* ws = (char*)d_ws;
    float*          Zcat  = (float*)ws;
    float*          T     = (float*)(ws + 32768);
    unsigned short* Wh    = (unsigned short*)(ws + 32768 + 2097152);
    unsigned short* Wl    = (unsigned short*)(ws + 32768 + 2097152 + 65536);
    unsigned short* expB  = (unsigned short*)(ws + 2260992);
    unsigned short* expVT = (unsigned short*)(ws + 2260992 + 33554432);
    unsigned short* Gth   = expB;                    // alias (after k3)
    unsigned short* Gtm   = expB + 128 * 128 * 32;
    unsigned short* Gtl   = expB + 2 * 128 * 128 * 32;

    hipMemsetAsync(Zcat, 0, 32768 + 2097152, stream);   // Zcat + T

    k0_prep<<<dim3(32),     256, 0, stream>>>(wB, wV, Wh, Wl);
    k1_bv  <<<dim3(64, 32), 256, 0, stream>>>(x, Wh, Wl, bB, bV, expB, expVT, Zcat);
    k3_T   <<<dim3(16, 32), 256, 0, stream>>>(expB, x, T);
    k3b_G  <<<dim3(4, 32),  256, 0, stream>>>(T, wA, bA, Zcat, Gth, Gtm, Gtl);
    k4_out <<<dim3(32, 32), 256, 0, stream>>>(expVT, Gth, Gtm, Gtl, out);
}

// Round 4
// 262.579 us; speedup vs baseline: 1.3175x; 1.1593x over previous
//
#include <hip/hip_runtime.h>
#include <hip/hip_bf16.h>

// B=32, C=128, HW=4096.
//   E = [wB;wV]@x + bias ; expB/expV = exp(E) (bf16) ; ZB/ZV row sums
//   T[i,c] = sum_n expB[i,n]*x[c,n]
//   G[i,j] = ((T[i,:].wA[j,:])/ZB_i + bA[j]) / (4096*ZV_i)
//   out[j,n] = sum_i expV[i,n]*G[i,j]
// Round 4: k1+k3 fused. Per block (b, 256-n chunk), 8 subtiles of 32 n:
//   stage x hi/lo in BOTH layouts -> E-MFMA -> exp epilogue (expB/expV to LDS,
//   Z in regs) -> T-MFMA (K=32, acc in regs) -> expVT copy-out. T/Z atomics once
//   at block end. expB never goes to HBM; x read once.

#define B_  32
#define C_  128
#define HW_ 4096

typedef __attribute__((ext_vector_type(8))) __bf16 bf16x8;
typedef __attribute__((ext_vector_type(4))) float f32x4;

__device__ __forceinline__ unsigned int bf_rne(float f) {   // bf16 bits (RNE)
    unsigned int u = __float_as_uint(f);
    return (u + 0x7fffu + ((u >> 16) & 1u)) >> 16;
}
__device__ __forceinline__ float bf_hi(float f) {           // RNE-to-bf16, as fp32
    unsigned int u = __float_as_uint(f);
    return __uint_as_float((u + 0x7fffu + ((u >> 16) & 1u)) & 0xffff0000u);
}

// ---------------------------------------------------------------------------
// k0: split Wcat=[wB;wV] (256x128 fp32) into bf16 hi/lo arrays. grid 32x256.
__global__ __launch_bounds__(256) void k0_prep(
    const float* __restrict__ wB, const float* __restrict__ wV,
    unsigned short* __restrict__ Wh, unsigned short* __restrict__ Wl)
{
    int g = blockIdx.x * 256 + threadIdx.x;      // 0..8191 float4s
    int row = g >> 5, c4 = (g & 31) << 2;
    const float* src = (row < 128) ? &wB[row * 128] : &wV[(row - 128) * 128];
    float4 v = *(const float4*)&src[c4];
    float vv[4] = {v.x, v.y, v.z, v.w};
    unsigned int h[4], l[4];
#pragma unroll
    for (int e = 0; e < 4; ++e) {
        float hf = bf_hi(vv[e]);
        h[e] = __float_as_uint(hf) >> 16;
        l[e] = bf_rne(vv[e] - hf);
    }
    *(uint2*)&Wh[row * 128 + c4] = make_uint2(h[0] | (h[1] << 16), h[2] | (h[3] << 16));
    *(uint2*)&Wl[row * 128 + c4] = make_uint2(l[0] | (l[1] << 16), l[2] | (l[3] << 16));
}

// ---------------------------------------------------------------------------
// k1_fused: E-GEMM + exp + Z + T-GEMM, grid (16 nchunks, 32 b), 256 thr = 4 waves.
__global__ __launch_bounds__(256) void k1_fused(
    const float* __restrict__ x,
    const unsigned short* __restrict__ Wh, const unsigned short* __restrict__ Wl,
    const float* __restrict__ bB, const float* __restrict__ bV,
    unsigned short* __restrict__ expVT, float* __restrict__ T,
    float* __restrict__ Zcat)
{
    __shared__ unsigned short XT_h[32 * 136];   // [n][c] pitch 136 (E B-operand, hi)
    __shared__ unsigned short XT_l[32 * 136];
    __shared__ unsigned short XN_h[128 * 40];   // [c][n] pitch 40 (T B-operand, hi)
    __shared__ unsigned short XN_l[128 * 40];
    __shared__ unsigned short EBs[128 * 40];    // expB [i][n] pitch 40 (T A-operand)
    __shared__ unsigned short EVs[32 * 136];    // expV [n][i] pitch 136 (copy-out)

    const int t = threadIdx.x;
    const int lane = t & 63, w = t >> 6;
    const int col16 = lane & 15, quad = lane >> 4;
    const int b = blockIdx.y;
    const int n0 = blockIdx.x * 256;
    const float* xb = x + (size_t)b * C_ * HW_;

    const int sn = t & 31;        // staging: this thread's n within subtile
    const int cq0 = t >> 5;       // staging: c-block base (0..7)

    const int rowbase = w * 64;               // E rows for this wave (0..255)
    const int mh = (w >> 1) * 64;             // T tile: i-half
    const int nh = (w & 1) * 64;              // T tile: c-half
    const float* bptr = (w < 2) ? bB : bV;
    const int lbase = (w & 1) * 64;           // row base within 128-row projection

    float biasr[4][4];
#pragma unroll
    for (int mt = 0; mt < 4; ++mt)
#pragma unroll
        for (int r = 0; r < 4; ++r)
            biasr[mt][r] = bptr[lbase + mt * 16 + quad * 4 + r];

    f32x4 tacc[4][4];
    float zacc[4][4];
#pragma unroll
    for (int i = 0; i < 4; ++i)
#pragma unroll
        for (int j = 0; j < 4; ++j) { tacc[i][j] = (f32x4){0.f,0.f,0.f,0.f}; zacc[i][j] = 0.f; }

    // prefetch subtile 0: thread owns x[c = (cq0+8*i2)*8 + cc][n0 + sn]
    float xr[16];
#pragma unroll
    for (int i2 = 0; i2 < 2; ++i2)
#pragma unroll
        for (int cc = 0; cc < 8; ++cc)
            xr[i2 * 8 + cc] = xb[(size_t)((cq0 + i2 * 8) * 8 + cc) * HW_ + n0 + sn];

    for (int st = 0; st < 8; ++st) {
        // convert this subtile's x to bf16 hi/lo
        unsigned int hbits[16], lbits[16];
#pragma unroll
        for (int e = 0; e < 16; ++e) {
            float hf = bf_hi(xr[e]);
            hbits[e] = __float_as_uint(hf) >> 16;
            lbits[e] = bf_rne(xr[e] - hf);
        }
        __syncthreads();   // previous subtile's T-MFMA / copy-out done
        // XT [n][c]: one uint4 (8 consecutive c) per i2 -> clean b128 writes
#pragma unroll
        for (int i2 = 0; i2 < 2; ++i2) {
            const unsigned int* h = &hbits[i2 * 8];
            const unsigned int* l = &lbits[i2 * 8];
            int cb = (cq0 + i2 * 8) * 8;
            *(uint4*)&XT_h[sn * 136 + cb] = make_uint4(
                h[0] | (h[1] << 16), h[2] | (h[3] << 16), h[4] | (h[5] << 16), h[6] | (h[7] << 16));
            *(uint4*)&XT_l[sn * 136 + cb] = make_uint4(
                l[0] | (l[1] << 16), l[2] | (l[3] << 16), l[4] | (l[5] << 16), l[6] | (l[7] << 16));
            // XN [c][n]: scalar b16 scatter (~4-way, 32 instrs)
#pragma unroll
            for (int cc = 0; cc < 8; ++cc) {
                int c = cb + cc;
                XN_h[c * 40 + sn] = (unsigned short)h[cc];
                XN_l[c * 40 + sn] = (unsigned short)l[cc];
            }
        }
        __syncthreads();
        // prefetch next subtile (overlaps E/T compute)
        if (st < 7) {
            int ns2 = n0 + (st + 1) * 32;
#pragma unroll
            for (int i2 = 0; i2 < 2; ++i2)
#pragma unroll
                for (int cc = 0; cc < 8; ++cc)
                    xr[i2 * 8 + cc] = xb[(size_t)((cq0 + i2 * 8) * 8 + cc) * HW_ + ns2 + sn];
        }

        // --- E-GEMM: wave computes rows rowbase..+63 x 32 n, K=128 (c), 3 terms
        f32x4 eacc[4][2];
#pragma unroll
        for (int i = 0; i < 4; ++i)
#pragma unroll
            for (int j = 0; j < 2; ++j) eacc[i][j] = (f32x4){0.f,0.f,0.f,0.f};
#pragma unroll
        for (int ks = 0; ks < 4; ++ks) {
            int kc = ks * 32 + quad * 8;
            bf16x8 wh[4], wl[4], xh[2], xl[2];
#pragma unroll
            for (int mt = 0; mt < 4; ++mt) {
                int row = rowbase + mt * 16 + col16;
                wh[mt] = *(const bf16x8*)&Wh[row * 128 + kc];
                wl[mt] = *(const bf16x8*)&Wl[row * 128 + kc];
            }
#pragma unroll
            for (int nt = 0; nt < 2; ++nt) {
                int nl = nt * 16 + col16;
                xh[nt] = *(const bf16x8*)&XT_h[nl * 136 + kc];
                xl[nt] = *(const bf16x8*)&XT_l[nl * 136 + kc];
            }
#pragma unroll
            for (int mt = 0; mt < 4; ++mt)
#pragma unroll
                for (int nt = 0; nt < 2; ++nt) {
                    eacc[mt][nt] = __builtin_amdgcn_mfma_f32_16x16x32_bf16(wh[mt], xh[nt], eacc[mt][nt], 0, 0, 0);
                    eacc[mt][nt] = __builtin_amdgcn_mfma_f32_16x16x32_bf16(wh[mt], xl[nt], eacc[mt][nt], 0, 0, 0);
                    eacc[mt][nt] = __builtin_amdgcn_mfma_f32_16x16x32_bf16(wl[mt], xh[nt], eacc[mt][nt], 0, 0, 0);
                }
        }

        // --- epilogue: exp, Z accumulate, expB->EBs / expV->EVs
#pragma unroll
        for (int mt = 0; mt < 4; ++mt)
#pragma unroll
            for (int r = 0; r < 4; ++r) {
                int lrow = lbase + mt * 16 + quad * 4 + r;   // 0..127 within proj
                float e0 = __expf(eacc[mt][0][r] + biasr[mt][r]);
                float e1 = __expf(eacc[mt][1][r] + biasr[mt][r]);
                zacc[mt][r] += e0 + e1;
                if (w < 2) {
                    EBs[lrow * 40 + col16]      = (unsigned short)bf_rne(e0);
                    EBs[lrow * 40 + 16 + col16] = (unsigned short)bf_rne(e1);
                } else {
                    EVs[col16 * 136 + lrow]        = (unsigned short)bf_rne(e0);
                    EVs[(16 + col16) * 136 + lrow] = (unsigned short)bf_rne(e1);
                }
            }
        __syncthreads();   // EBs/EVs ready; XN still valid

        // --- T-GEMM: K=32 (this subtile's n), wave tile 64 i x 64 c
        {
            bf16x8 a[4], bh[4], bl[4];
#pragma unroll
            for (int mt = 0; mt < 4; ++mt)
                a[mt] = *(const bf16x8*)&EBs[(mh + mt * 16 + col16) * 40 + quad * 8];
#pragma unroll
            for (int ct = 0; ct < 4; ++ct) {
                int c = nh + ct * 16 + col16;
                bh[ct] = *(const bf16x8*)&XN_h[c * 40 + quad * 8];
                bl[ct] = *(const bf16x8*)&XN_l[c * 40 + quad * 8];
            }
#pragma unroll
            for (int mt = 0; mt < 4; ++mt)
#pragma unroll
                for (int ct = 0; ct < 4; ++ct) {
                    tacc[mt][ct] = __builtin_amdgcn_mfma_f32_16x16x32_bf16(a[mt], bh[ct], tacc[mt][ct], 0, 0, 0);
                    tacc[mt][ct] = __builtin_amdgcn_mfma_f32_16x16x32_bf16(a[mt], bl[ct], tacc[mt][ct], 0, 0, 0);
                }
        }
        // --- expVT copy-out (32 n x 128 i)
#pragma unroll
        for (int it = 0; it < 2; ++it) {
            int idx = it * 256 + t;
            int n = idx >> 4, ig = idx & 15;
            *(uint4*)&expVT[((size_t)b * HW_ + n0 + st * 32 + n) * 128 + ig * 8] =
                *(const uint4*)&EVs[n * 136 + ig * 8];
        }
    }

    // Z atomics (one per row, reduced across col16 lanes first)
    const int zoff = (w < 2) ? 0 : 128;
#pragma unroll
    for (int mt = 0; mt < 4; ++mt)
#pragma unroll
        for (int r = 0; r < 4; ++r) {
            float rs = zacc[mt][r];
            rs += __shfl_xor(rs, 1, 16);
            rs += __shfl_xor(rs, 2, 16);
            rs += __shfl_xor(rs, 4, 16);
            rs += __shfl_xor(rs, 8, 16);
            if (col16 == 0)
                atomicAdd(&Zcat[b * 256 + zoff + lbase + mt * 16 + quad * 4 + r], rs);
        }
    // T atomics
#pragma unroll
    for (int mt = 0; mt < 4; ++mt)
#pragma unroll
        for (int ct = 0; ct < 4; ++ct)
#pragma unroll
            for (int r = 0; r < 4; ++r)
                atomicAdd(&T[((size_t)b * 128 + mh + mt * 16 + quad * 4 + r) * 128 + nh + ct * 16 + col16],
                          tacc[mt][ct][r]);
}

// ---------------------------------------------------------------------------
// k3b: G transposed + 3-way bf16 split. grid (4, 32), block 256, fp32 VALU.
__global__ __launch_bounds__(256) void k3b_G(
    const float* __restrict__ T, const float* __restrict__ wA, const float* __restrict__ bA,
    const float* __restrict__ Zcat,
    unsigned short* __restrict__ Gth, unsigned short* __restrict__ Gtm,
    unsigned short* __restrict__ Gtl)
{
    const int t = threadIdx.x;
    const int tx = t & 15, ty = t >> 4;
    const int b = blockIdx.y;
    const int jb = (blockIdx.x >> 1) * 64;
    const int ib = (blockIdx.x & 1) * 64;

    __shared__ float Ts[64][36];
    __shared__ float Wa[64][36];

    float acc[4][4];
#pragma unroll
    for (int i = 0; i < 4; ++i)
#pragma unroll
        for (int j = 0; j < 4; ++j) acc[i][j] = 0.f;

    for (int c0 = 0; c0 < 128; c0 += 32) {
        __syncthreads();
#pragma unroll
        for (int it = 0; it < 2; ++it) {
            int idx = it * 256 + t;
            int r = idx >> 3, kq = (idx & 7) << 2;
            *(float4*)&Ts[r][kq] = *(const float4*)&T[((size_t)b * 128 + ib + r) * 128 + c0 + kq];
        }
#pragma unroll
        for (int it = 0; it < 2; ++it) {
            int idx = it * 256 + t;
            int r = idx >> 3, kq = (idx & 7) << 2;
            *(float4*)&Wa[r][kq] = *(const float4*)&wA[(jb + r) * 128 + c0 + kq];
        }
        __syncthreads();
#pragma unroll
        for (int k = 0; k < 32; k += 4) {
            float4 wv[4], tv[4];
#pragma unroll
            for (int jj = 0; jj < 4; ++jj) wv[jj] = *(const float4*)&Wa[jj * 16 + ty][k];
#pragma unroll
            for (int ii = 0; ii < 4; ++ii) tv[ii] = *(const float4*)&Ts[ii * 16 + tx][k];
#pragma unroll
            for (int jj = 0; jj < 4; ++jj)
#pragma unroll
                for (int ii = 0; ii < 4; ++ii) {
                    acc[jj][ii] = fmaf(wv[jj].x, tv[ii].x, acc[jj][ii]);
                    acc[jj][ii] = fmaf(wv[jj].y, tv[ii].y, acc[jj][ii]);
                    acc[jj][ii] = fmaf(wv[jj].z, tv[ii].z, acc[jj][ii]);
                    acc[jj][ii] = fmaf(wv[jj].w, tv[ii].w, acc[jj][ii]);
                }
        }
    }
    const float* ZB = Zcat + b * 256;
    const float* ZV = ZB + 128;
#pragma unroll
    for (int jj = 0; jj < 4; ++jj) {
        int j = jb + jj * 16 + ty;
        float bj = bA[j];
#pragma unroll
        for (int ii = 0; ii < 4; ++ii) {
            int i = ib + ii * 16 + tx;
            float g = (acc[jj][ii] / ZB[i] + bj) / (4096.f * ZV[i]);
            float h = bf_hi(g);  float r1 = g - h;
            float m = bf_hi(r1); float r2 = r1 - m;
            size_t o = ((size_t)b * 128 + j) * 128 + i;
            Gth[o] = (unsigned short)(__float_as_uint(h) >> 16);
            Gtm[o] = (unsigned short)(__float_as_uint(m) >> 16);
            Gtl[o] = (unsigned short)bf_rne(r2);
        }
    }
}

// ---------------------------------------------------------------------------
// k4: out[b,j,n] = sum_i expVT[n][i] * Gt(j,i)  (MFMA, 3-term G split).
__global__ __launch_bounds__(256) void k4_out(
    const unsigned short* __restrict__ expVT,
    const unsigned short* __restrict__ Gth, const unsigned short* __restrict__ Gtm,
    const unsigned short* __restrict__ Gtl, float* __restrict__ out)
{
    __shared__ unsigned short Vs[128 * 136];   // [n][i] pitch 136

    const int t = threadIdx.x;
    const int lane = t & 63, w = t >> 6;
    const int col16 = lane & 15, quad = lane >> 4;
    const int b = blockIdx.y, nb = blockIdx.x * 128;

#pragma unroll
    for (int it = 0; it < 8; ++it) {
        int idx = it * 256 + t;
        int n = idx >> 4, o = idx & 15;
        int o2 = (o + 4 * (n & 3)) & 15;
        *(uint4*)&Vs[n * 136 + o2 * 8] =
            *(const uint4*)&expVT[((size_t)b * HW_ + nb + n) * 128 + o2 * 8];
    }
    __syncthreads();

    f32x4 acc[8][2];
#pragma unroll
    for (int i = 0; i < 8; ++i)
#pragma unroll
        for (int j = 0; j < 2; ++j) acc[i][j] = (f32x4){0.f,0.f,0.f,0.f};

    const unsigned short* gh = Gth + (size_t)b * 128 * 128;
    const unsigned short* gm = Gtm + (size_t)b * 128 * 128;
    const unsigned short* gl = Gtl + (size_t)b * 128 * 128;

#pragma unroll
    for (int ks = 0; ks < 4; ++ks) {
        int ko = ks * 32 + quad * 8;
        bf16x8 vfr[2];
#pragma unroll
        for (int nt = 0; nt < 2; ++nt) {
            int n = w * 32 + nt * 16 + col16;
            vfr[nt] = *(const bf16x8*)&Vs[n * 136 + ko];
        }
#pragma unroll
        for (int mt = 0; mt < 8; ++mt) {
            int j = mt * 16 + col16;
            bf16x8 ah = *(const bf16x8*)&gh[j * 128 + ko];
            bf16x8 am = *(const bf16x8*)&gm[j * 128 + ko];
            bf16x8 al = *(const bf16x8*)&gl[j * 128 + ko];
#pragma unroll
            for (int nt = 0; nt < 2; ++nt) {
                acc[mt][nt] = __builtin_amdgcn_mfma_f32_16x16x32_bf16(ah, vfr[nt], acc[mt][nt], 0, 0, 0);
                acc[mt][nt] = __builtin_amdgcn_mfma_f32_16x16x32_bf16(am, vfr[nt], acc[mt][nt], 0, 0, 0);
                acc[mt][nt] = __builtin_amdgcn_mfma_f32_16x16x32_bf16(al, vfr[nt], acc[mt][nt], 0, 0, 0);
            }
        }
    }
    float* ob = out + (size_t)b * C_ * HW_;
#pragma unroll
    for (int mt = 0; mt < 8; ++mt)
#pragma unroll
        for (int nt = 0; nt < 2; ++nt)
#pragma unroll
            for (int r = 0; r < 4; ++r) {
                int j = mt * 16 + quad * 4 + r;
                int n = nb + w * 32 + nt * 16 + col16;
                ob[(size_t)j * HW_ + n] = acc[mt][nt][r];
            }
}

// ---------------------------------------------------------------------------
extern "C" void kernel_launch(void* const* d_in, const int* in_sizes, int n_in,
                              void* d_out, int out_size, void* d_ws, size_t ws_size,
                              hipStream_t stream)
{
    const float* x  = (const float*)d_in[0];
    const float* wA = (const float*)d_in[1];
    const float* bA = (const float*)d_in[2];
    const float* wB = (const float*)d_in[3];
    const float* bB = (const float*)d_in[4];
    const float* wV = (const float*)d_in[5];
    const float* bV = (const float*)d_in[6];
    float* out = (float*)d_out;

    // workspace (~39 MiB):
    //   Zcat 32 KiB | T 2 MiB | Wh 64 KiB | Wl 64 KiB | expVT 32 MiB | Gth/Gtm/Gtl 3 MiB
    char* ws = (char*)d_ws;
    float*          Zcat  = (float*)ws;
    float*          T     = (float*)(ws + 32768);
    unsigned short* Wh    = (unsigned short*)(ws + 2129920);
    unsigned short* Wl    = (unsigned short*)(ws + 2195456);
    unsigned short* expVT = (unsigned short*)(ws + 2260992);
    unsigned short* Gth   = (unsigned short*)(ws + 2260992 + 33554432);
    unsigned short* Gtm   = Gth + 128 * 128 * 32;
    unsigned short* Gtl   = Gth + 2 * 128 * 128 * 32;

    hipMemsetAsync(Zcat, 0, 2129920, stream);   // Zcat + T

    k0_prep <<<dim3(32),     256, 0, stream>>>(wB, wV, Wh, Wl);
    k1_fused<<<dim3(16, 32), 256, 0, stream>>>(x, Wh, Wl, bB, bV, expVT, T, Zcat);
    k3b_G   <<<dim3(4, 32),  256, 0, stream>>>(T, wA, bA, Zcat, Gth, Gtm, Gtl);
    k4_out  <<<dim3(32, 32), 256, 0, stream>>>(expVT, Gth, Gtm, Gtl, out);
}